// Round 2
// baseline (398.892 us; speedup 1.0000x reference)
//
#include <hip/hip_runtime.h>

// CRF loss forward on MI355X.
// scores (512,128,48,48) f32, target (512,128) int, mask (512,128) int -> scalar f32
// One block per batch (serial scan over s). Deep global_load_lds ring pipeline:
//   - 9 waves (576 thr); wave w DMAs chunk w (1024B) of tile s+DPTH each step
//   - counted s_waitcnt vmcnt(DPTH-1) + RAW s_barrier (no vmcnt(0) drain)
//   - ONE barrier per step: write partials(s) -> barrier -> combine(s) + read tile(s+1)
//   - p kept in registers (lane j holds p[j]) redundantly per wave; __shfl for p[i]
//   - wave 8 = producer-ish: handles target-energy gather (pipelined idx)

#define S_LEN 512
#define BATCH 128
#define T 48
#define TT 2304
#define TROW 2320          // padded row so lane 48..63 garbage reads stay in-bounds
#define START_TAG 46
#define END_TAG 47
#define NT 576             // 9 waves
#define DPTH 5             // prefetch depth (tiles in flight)
#define RING 6             // ring buffers (> DPTH)

__device__ __forceinline__ void gl_lds16(const float* g, float* l) {
  __builtin_amdgcn_global_load_lds(
      (const __attribute__((address_space(1))) void*)g,
      (__attribute__((address_space(3))) void*)l, 16, 0, 0);
}

// raw barrier: drain LDS ops for cross-wave visibility, but DO NOT drain vmcnt
#define BARRIER() asm volatile("s_waitcnt lgkmcnt(0)\n\ts_barrier" ::: "memory")
// certify oldest in-flight tile (DPTH outstanding -> wait until DPTH-1)
#define WAIT_VM() asm volatile("s_waitcnt vmcnt(4)" ::: "memory")

__global__ __launch_bounds__(NT) void crf_scan(
    const float* __restrict__ scores, const int* __restrict__ target,
    const int* __restrict__ mask, float* __restrict__ ws)
{
  __shared__ float tile[RING][TROW];
  __shared__ float red_m[2][8][T];
  __shared__ float red_s[2][8][T];
  __shared__ int lmask[S_LEN];
  __shared__ int ltgt[S_LEN];
  __shared__ float dummy[256];
  __shared__ float tg_share;

  const int b = blockIdx.x;
  const int t = threadIdx.x;
  const int lane = t & 63;
  const int wid = __builtin_amdgcn_readfirstlane(t >> 6);  // provably wave-uniform

  if (t < S_LEN) {
    lmask[t] = mask[(size_t)t * BATCH + b];
    ltgt[t]  = target[(size_t)t * BATCH + b];
  }
  __syncthreads();  // prologue-only: masks visible, vmcnt fully drained (count = 0)

  const float* sb = scores + (size_t)b * TT;
  const size_t sstride = (size_t)BATCH * TT;

  // prologue: issue tiles 0..DPTH-1 (wave w -> chunk w: 256 floats at w*256)
#pragma unroll
  for (int pt = 0; pt < DPTH; ++pt)
    gl_lds16(sb + (size_t)pt * sstride + wid * 256 + lane * 4, &tile[pt][wid * 256]);
  WAIT_VM();
  BARRIER();  // tile[0] certified

  float p = tile[0][START_TAG * T + lane];  // lane j holds p[j] (j<48 valid)
  float tg = 0.0f;
  int nextIdx = ltgt[1];
  if (wid == 8 && lane == 0 && lmask[0]) tg = tile[0][ltgt[0]];

  // body(0): issue tile DPTH, certify tile[1]
  gl_lds16(sb + (size_t)DPTH * sstride + wid * 256 + lane * 4,
           &tile[DPTH % RING][wid * 256]);
  WAIT_VM();
  BARRIER();  // tile[1] certified

  for (int s = 1; s < S_LEN; ++s) {
    const int slot = s % RING;
    const int par = s & 1;
    const int msk = lmask[s];

    if (wid < 8) {
      // partials for step s: rows i0..i0+5, this lane's column j = lane
      const int i0 = wid * 6;
      const float x0 = tile[slot][(i0 + 0) * T + lane] + __shfl(p, i0 + 0, 64);
      const float x1 = tile[slot][(i0 + 1) * T + lane] + __shfl(p, i0 + 1, 64);
      const float x2 = tile[slot][(i0 + 2) * T + lane] + __shfl(p, i0 + 2, 64);
      const float x3 = tile[slot][(i0 + 3) * T + lane] + __shfl(p, i0 + 3, 64);
      const float x4 = tile[slot][(i0 + 4) * T + lane] + __shfl(p, i0 + 4, 64);
      const float x5 = tile[slot][(i0 + 5) * T + lane] + __shfl(p, i0 + 5, 64);
      const float m = fmaxf(fmaxf(fmaxf(x0, x1), fmaxf(x2, x3)), fmaxf(x4, x5));
      const float sum = __expf(x0 - m) + __expf(x1 - m) + __expf(x2 - m) +
                        __expf(x3 - m) + __expf(x4 - m) + __expf(x5 - m);
      if (lane < T) {
        red_m[par][wid][lane] = m;
        red_s[par][wid][lane] = sum;
      }
    } else if (lane == 0) {
      // target-energy gather on the extra wave (idx read pipelined one step ahead)
      const int idx = nextIdx;
      nextIdx = ltgt[(s + 1) & (S_LEN - 1)];
      if (msk) tg += tile[slot][idx];
    }

    // issue tile s+DPTH (clamped source / dummy dest past the end keeps vmcnt math constant)
    {
      const int pt = s + DPTH;
      const int srcT = (pt < S_LEN) ? pt : (S_LEN - 1);
      float* ld = (pt < S_LEN) ? &tile[pt % RING][wid * 256] : &dummy[0];
      gl_lds16(sb + (size_t)srcT * sstride + wid * 256 + lane * 4, ld);
    }
    WAIT_VM();
    BARRIER();  // tile[s+1] certified; red[par] visible

    // combine (redundant in every compute wave -> p stays in registers, no 2nd barrier)
    if (wid < 8 && lane < T) {
      float M = red_m[par][0][lane];
#pragma unroll
      for (int g2 = 1; g2 < 8; ++g2) M = fmaxf(M, red_m[par][g2][lane]);
      float Ssum = 0.0f;
#pragma unroll
      for (int g2 = 0; g2 < 8; ++g2)
        Ssum += red_s[par][g2][lane] * __expf(red_m[par][g2][lane] - M);
      if (msk) p = M + __logf(Ssum);
    }
  }

  if (wid == 8 && lane == 0) tg_share = tg;
  BARRIER();
  if (t == END_TAG) ws[b] = p - tg_share;  // t==47: wave 0, lane END_TAG

  // drain tail dummy DMAs before LDS is deallocated
  asm volatile("s_waitcnt vmcnt(0)" ::: "memory");
}

__global__ void crf_reduce(const float* __restrict__ ws, float* __restrict__ out)
{
  __shared__ float sh[BATCH];
  const int t = threadIdx.x;
  if (t < BATCH) sh[t] = ws[t];
  __syncthreads();
  if (t == 0) {
    float s = 0.0f;
    for (int k = 0; k < BATCH; ++k) s += sh[k];
    out[0] = s / (float)BATCH;
  }
}

extern "C" void kernel_launch(void* const* d_in, const int* in_sizes, int n_in,
                              void* d_out, int out_size, void* d_ws, size_t ws_size,
                              hipStream_t stream)
{
  const float* scores = (const float*)d_in[0];
  const int* target = (const int*)d_in[1];
  const int* mask = (const int*)d_in[2];
  float* ws = (float*)d_ws;
  float* out = (float*)d_out;

  crf_scan<<<BATCH, NT, 0, stream>>>(scores, target, mask, ws);
  crf_reduce<<<1, 128, 0, stream>>>(ws, out);
}

// Round 3
// 179.689 us; speedup vs baseline: 2.2199x; 2.2199x over previous
//
#include <hip/hip_runtime.h>

// CRF loss forward, chunked log-semiring matrix-product formulation.
// scores (512,128,48,48) f32, target (512,128) int32, mask (512,128) int32 -> scalar f32
//
// p_final^T = p0^T · M_1 · ... · M_511  (log-semiring). Work in EXP space:
//   E_s = exp(S_s) (identity for s==0 or masked). Phase 1: 2048 independent
//   waves each compute one (chunk c, batch b) product of 32 matrices via
//   bf16 MFMA (16x16x32), scaling each matmul by 2^-7 (exact) to bound range;
//   log-correction 496*7*ln2 is a compile-time constant added at the end.
// Phase 2: per-batch fold of 16 chunk matrices. Phase 3: deterministic reduce.

#define S_LEN 512
#define BATCH 128
#define T 48
#define TT 2304
#define START_TAG 46
#define END_TAG 47

#define CHUNK 32
#define NCHUNK 16
#define NTASK (NCHUNK * BATCH)      // 2048
#define P1_WAVES 4
#define P1_THREADS 256
#define P1_BLOCKS (NTASK / P1_WAVES) // 512
#define SIGMA 0.0078125f             // 2^-7, exact per-matmul scale

typedef float f32x4 __attribute__((ext_vector_type(4)));
typedef short bf16x8 __attribute__((ext_vector_type(8)));

__device__ __forceinline__ void gl_lds16(const float* g, float* l) {
  __builtin_amdgcn_global_load_lds(
      (const __attribute__((address_space(1))) void*)g,
      (__attribute__((address_space(3))) void*)l, 16, 0, 0);
}

__device__ __forceinline__ void stage_tile(const float* g, float* l, int lane) {
#pragma unroll
  for (int it = 0; it < 9; ++it)
    gl_lds16(g + it * 256 + lane * 4, l + it * 256);
}

__device__ __forceinline__ short f2bf(float x) {  // RTNE f32->bf16 bits
  unsigned u = __float_as_uint(x);
  u = (u + 0x7fffu + ((u >> 16) & 1u)) >> 16;
  return (short)u;
}

// ---------------- Phase 1: per-chunk matrix product ----------------
__global__ __launch_bounds__(P1_THREADS) void crf_chunk(
    const float* __restrict__ scores, const int* __restrict__ target,
    const int* __restrict__ mask, float* __restrict__ Rbuf,
    float* __restrict__ tgbuf)
{
  __shared__ float lds[P1_WAVES][2][TT];
  const int t = threadIdx.x;
  const int lane = t & 63;
  const int wid = __builtin_amdgcn_readfirstlane(t >> 6);
  const int g = lane >> 4;   // 0..3
  const int c15 = lane & 15; // 0..15

  const int task = blockIdx.x * P1_WAVES + wid;
  const int b = task & (BATCH - 1);
  const int cIdx = task >> 7;
  const int s0 = cIdx * CHUNK;

  // mask (lanes 0..31) / target (lanes 32..63) for this chunk, one reg
  int mt;
  {
    int sl = s0 + (lane & 31);
    mt = (lane < 32) ? mask[(size_t)sl * BATCH + b]
                     : target[(size_t)sl * BATCH + b];
  }

  const float* sbase = scores + ((size_t)s0 * BATCH + b) * TT;
  float* l0 = &lds[wid][0][0];
  float* l1 = &lds[wid][1][0];

  stage_tile(sbase, l0, lane);                      // tile 0
  stage_tile(sbase + (size_t)1 * BATCH * TT, l1, lane); // tile 1
  asm volatile("s_waitcnt vmcnt(9)" ::: "memory");  // tile0 (and m/t) done

  // ---- init B = E_{s0} (B[k][col] = E[col][k]); identity if s0==0 or masked
  const int msk0 = __shfl(mt, 0, 64);
  const bool id0 = (s0 == 0) || (msk0 == 0);
  bf16x8 Bf[2][3];
#pragma unroll
  for (int tk = 0; tk < 2; ++tk)
#pragma unroll
    for (int tj = 0; tj < 3; ++tj) {
      bf16x8 bv;
#pragma unroll
      for (int i = 0; i < 8; ++i) {
        int kk = 32 * tk + 8 * g + i;
        int col = 16 * tj + c15;
        float val = 0.f;
        if (kk < T) val = id0 ? ((kk == col) ? 1.f : 0.f) : __expf(l0[col * T + kk]);
        bv[i] = f2bf(val);
      }
      Bf[tk][tj] = bv;
    }

  float tgacc = 0.f;
  { // tg gather for matrix s0 (uses raw tile 0 before overwrite)
    int tg0 = __shfl(mt, 32, 64);
    if (lane == 0 && msk0) tgacc += l0[tg0];
  }
  asm volatile("s_waitcnt lgkmcnt(0)" ::: "memory");
  stage_tile(sbase + (size_t)2 * BATCH * TT, l0, lane); // tile 2 -> slot 0

  f32x4 Cf[3][3];
  const f32x4 zz = {0.f, 0.f, 0.f, 0.f};

#pragma unroll 1
  for (int k = 1; k < CHUNK; ++k) {
    float* cur = (k & 1) ? l1 : l0;
    if (k == CHUNK - 1) asm volatile("s_waitcnt vmcnt(0)" ::: "memory");
    else                asm volatile("s_waitcnt vmcnt(9)" ::: "memory");

    const int msk = __shfl(mt, k, 64);
    const int tgt = __shfl(mt, 32 + k, 64);
    const bool ident = (msk == 0);

    // A-frags: A[j][kk] = sigma * E_k[kk][j]  (A = sigma * E^T); ident -> sigma*I
    bf16x8 Af[3][2];
#pragma unroll
    for (int ti = 0; ti < 3; ++ti)
#pragma unroll
      for (int tk = 0; tk < 2; ++tk) {
        bf16x8 av;
#pragma unroll
        for (int i = 0; i < 8; ++i) {
          int kk = 32 * tk + 8 * g + i;
          int j = 16 * ti + c15;
          float val = 0.f;
          if (kk < T)
            val = ident ? ((kk == j) ? SIGMA : 0.f)
                        : __expf(cur[kk * T + j]) * SIGMA;
          av[i] = f2bf(val);
        }
        Af[ti][tk] = av;
      }

    if (lane == 0 && msk) tgacc += cur[tgt];  // tg gather from raw tile

    asm volatile("s_waitcnt lgkmcnt(0)" ::: "memory");
    if (k + 2 < CHUNK)
      stage_tile(sbase + (size_t)(k + 2) * BATCH * TT, cur, lane);

    // R^T_new = (sigma E^T) . R^T   (9 output tiles, K=64 in 2 mfma)
#pragma unroll
    for (int ti = 0; ti < 3; ++ti)
#pragma unroll
      for (int tj = 0; tj < 3; ++tj) {
        f32x4 acc = __builtin_amdgcn_mfma_f32_16x16x32_bf16(Af[ti][0], Bf[0][tj], zz, 0, 0, 0);
        Cf[ti][tj] = __builtin_amdgcn_mfma_f32_16x16x32_bf16(Af[ti][1], Bf[1][tj], acc, 0, 0, 0);
      }

    // next B from C, register-only shuffles.
    // B[tk][tj] lane(g,c15) elem i = R^T[32tk+8g+i][16tj+c15]:
    //   ti_s = 2tk + (g>>1); src lane = 32(g&1) + 16(i>>2) + c15; reg r = i&3.
#pragma unroll
    for (int tj = 0; tj < 3; ++tj) {
      bf16x8 b0, b1;
      int srcLo = ((g & 1) << 5) + c15;
      int srcHi = srcLo + 16;
#pragma unroll
      for (int i = 0; i < 8; ++i) {
        int r = i & 3;
        int src = (i < 4) ? srcLo : srcHi;
        float a0 = __shfl(Cf[0][tj][r], src, 64);
        float a1 = __shfl(Cf[1][tj][r], src, 64);
        b0[i] = f2bf((g >> 1) ? a1 : a0);
        float a2 = __shfl(Cf[2][tj][r], src, 64);
        b1[i] = f2bf((g >> 1) ? 0.f : a2);
      }
      Bf[0][tj] = b0;
      Bf[1][tj] = b1;
    }
  }

  // write chunk product R^T (48x48, stored row-major [j][i])
  float* outp = Rbuf + (size_t)((size_t)cIdx * BATCH + b) * TT;
#pragma unroll
  for (int ti = 0; ti < 3; ++ti)
#pragma unroll
    for (int tj = 0; tj < 3; ++tj)
#pragma unroll
      for (int r = 0; r < 4; ++r) {
        int j = 16 * ti + 4 * g + r;
        int icol = 16 * tj + c15;
        outp[j * T + icol] = Cf[ti][tj][r];
      }

  if (lane == 0) tgbuf[task] = tgacc;
}

// ---------------- Phase 2: per-batch fold over 16 chunk matrices ----------------
__global__ __launch_bounds__(64) void crf_fold(
    const float* __restrict__ scores, const float* __restrict__ Rbuf,
    float* __restrict__ pend)
{
  __shared__ __align__(16) float e[T];
  const int b = blockIdx.x;
  const int j = threadIdx.x & 63;
  const int jr = (j < T) ? j : (T - 1);
  float p = (j < T) ? scores[(size_t)b * TT + START_TAG * T + j] : -1e30f;

  float4 bufA[12], bufB[12];
  {
    const float4* rA = (const float4*)(Rbuf + ((size_t)0 * BATCH + b) * TT + (size_t)jr * T);
#pragma unroll
    for (int q = 0; q < 12; ++q) bufA[q] = rA[q];
  }

#pragma unroll 1
  for (int c = 0; c < NCHUNK; c += 2) {
    const float4* rB = (const float4*)(Rbuf + ((size_t)(c + 1) * BATCH + b) * TT + (size_t)jr * T);
#pragma unroll
    for (int q = 0; q < 12; ++q) bufB[q] = rB[q];

    { // step c (bufA)
      float sh = __shfl(p, 0, 64);
      float ev = __expf(p - sh);
      if (j < T) e[j] = ev;
      asm volatile("s_waitcnt lgkmcnt(0)" ::: "memory");
      float acc = 0.f;
#pragma unroll
      for (int q = 0; q < 12; ++q) {
        float4 ef = ((const float4*)e)[q];
        acc += ef.x * bufA[q].x; acc += ef.y * bufA[q].y;
        acc += ef.z * bufA[q].z; acc += ef.w * bufA[q].w;
      }
      p = sh + __logf(acc);
    }
    if (c + 2 < NCHUNK) {
      const float4* rA = (const float4*)(Rbuf + ((size_t)(c + 2) * BATCH + b) * TT + (size_t)jr * T);
#pragma unroll
      for (int q = 0; q < 12; ++q) bufA[q] = rA[q];
    }
    { // step c+1 (bufB)
      float sh = __shfl(p, 0, 64);
      float ev = __expf(p - sh);
      if (j < T) e[j] = ev;
      asm volatile("s_waitcnt lgkmcnt(0)" ::: "memory");
      float acc = 0.f;
#pragma unroll
      for (int q = 0; q < 12; ++q) {
        float4 ef = ((const float4*)e)[q];
        acc += ef.x * bufB[q].x; acc += ef.y * bufB[q].y;
        acc += ef.z * bufB[q].z; acc += ef.w * bufB[q].w;
      }
      p = sh + __logf(acc);
    }
  }
  if (j == END_TAG) pend[b] = p;
}

// ---------------- Phase 3: deterministic reduce ----------------
__global__ void crf_final(const float* __restrict__ pend, const float* __restrict__ tgbuf,
                          float* __restrict__ out)
{
  __shared__ float sp[256], st2[256];
  int t = threadIdx.x;
  float ps = (t < BATCH) ? pend[t] : 0.f;
  float ts = 0.f;
  for (int q = t; q < NTASK; q += 256) ts += tgbuf[q];
  sp[t] = ps; st2[t] = ts;
  __syncthreads();
  for (int off = 128; off > 0; off >>= 1) {
    if (t < off) { sp[t] += sp[t + off]; st2[t] += st2[t + off]; }
    __syncthreads();
  }
  if (t == 0) {
    // 16 chunks * 31 matmuls * 7*ln2 (exact 2^-7 per-matmul scale)
    const float corr = 496.0f * 4.852030263919617f;
    out[0] = (sp[0] - st2[0]) / (float)BATCH + corr;
  }
}

// ---------------- Fallback (proven round-1 scan) for small ws ----------------
__global__ __launch_bounds__(512) void fb_scan(
    const float* __restrict__ scores, const int* __restrict__ target,
    const int* __restrict__ mask, float* __restrict__ ws)
{
  __shared__ float tile[2][TT];
  __shared__ float p[T];
  __shared__ float red_m[8][T];
  __shared__ float red_s[8][T];
  __shared__ int lmask[S_LEN];
  __shared__ int ltgt[S_LEN];

  const int b = blockIdx.x;
  const int t = threadIdx.x;
  const int j = t & 63;
  const int ic = t >> 6;
  const bool valid = (j < T);

  lmask[t] = mask[(size_t)t * BATCH + b];
  ltgt[t] = target[(size_t)t * BATCH + b];
  {
    const float4* src = (const float4*)(scores + (size_t)b * TT);
    float4 r0 = src[t]; float4 r1;
    if (t < 64) r1 = src[512 + t];
    float4* dst = (float4*)tile[0];
    dst[t] = r0;
    if (t < 64) dst[512 + t] = r1;
  }
  __syncthreads();
  float tg_local = 0.0f;
  for (int s = 0; s < S_LEN; ++s) {
    const int buf = s & 1;
    float4 r0, r1;
    if (s + 1 < S_LEN) {
      const float4* src = (const float4*)(scores + ((size_t)(s + 1) * BATCH + b) * TT);
      r0 = src[t];
      if (t < 64) r1 = src[512 + t];
    }
    if (s == 0) {
      if (t < T) p[t] = tile[0][START_TAG * T + t];
      if (t == 0 && lmask[0]) tg_local += tile[0][ltgt[0]];
    } else {
      if (valid) {
        const int i0 = ic * 6;
        float x[6]; float m = -1e30f;
#pragma unroll
        for (int k = 0; k < 6; ++k) {
          x[k] = tile[buf][(i0 + k) * T + j] + p[i0 + k];
          m = fmaxf(m, x[k]);
        }
        float sum = 0.0f;
#pragma unroll
        for (int k = 0; k < 6; ++k) sum += __expf(x[k] - m);
        red_m[ic][j] = m; red_s[ic][j] = sum;
      }
      if (t == 0 && lmask[s]) tg_local += tile[buf][ltgt[s]];
    }
    __syncthreads();
    if (s > 0 && t < T) {
      float M = red_m[0][t];
#pragma unroll
      for (int g2 = 1; g2 < 8; ++g2) M = fmaxf(M, red_m[g2][t]);
      float Ssum = 0.0f;
#pragma unroll
      for (int g2 = 0; g2 < 8; ++g2) Ssum += red_s[g2][t] * __expf(red_m[g2][t] - M);
      float cur = M + __logf(Ssum);
      if (lmask[s]) p[t] = cur;
    }
    if (s + 1 < S_LEN) {
      float4* dst = (float4*)tile[buf ^ 1];
      dst[t] = r0;
      if (t < 64) dst[512 + t] = r1;
    }
    __syncthreads();
  }
  if (t == 0) ws[b] = p[END_TAG] - tg_local;
}

__global__ void fb_reduce(const float* __restrict__ ws, float* __restrict__ out)
{
  __shared__ float sh[BATCH];
  const int t = threadIdx.x;
  if (t < BATCH) sh[t] = ws[t];
  __syncthreads();
  if (t == 0) {
    float s = 0.0f;
    for (int k = 0; k < BATCH; ++k) s += sh[k];
    out[0] = s / (float)BATCH;
  }
}

extern "C" void kernel_launch(void* const* d_in, const int* in_sizes, int n_in,
                              void* d_out, int out_size, void* d_ws, size_t ws_size,
                              hipStream_t stream)
{
  const float* scores = (const float*)d_in[0];
  const int* target = (const int*)d_in[1];
  const int* mask = (const int*)d_in[2];
  float* out = (float*)d_out;

  const size_t RB_FLOATS = (size_t)NTASK * TT;
  const size_t need = RB_FLOATS * 4 + (size_t)NTASK * 4 + (size_t)BATCH * 4;

  if (ws_size >= need) {
    float* Rbuf = (float*)d_ws;
    float* tgbuf = Rbuf + RB_FLOATS;
    float* pend = tgbuf + NTASK;
    crf_chunk<<<P1_BLOCKS, P1_THREADS, 0, stream>>>(scores, target, mask, Rbuf, tgbuf);
    crf_fold<<<BATCH, 64, 0, stream>>>(scores, Rbuf, pend);
    crf_final<<<1, 256, 0, stream>>>(pend, tgbuf, out);
  } else {
    float* ws = (float*)d_ws;
    fb_scan<<<BATCH, 512, 0, stream>>>(scores, target, mask, ws);
    fb_reduce<<<1, 128, 0, stream>>>(ws, out);
  }
}

// Round 4
// 163.161 us; speedup vs baseline: 2.4448x; 1.1013x over previous
//
#include <hip/hip_runtime.h>

// CRF loss forward, chunked log-semiring matrix-product formulation (register-direct).
// scores (512,128,48,48) f32, target (512,128) int32, mask (512,128) int32 -> scalar f32
//
// Phase 1: 2048 independent waves; wave (c,b) computes prod of 32 exp-space
//   transition matrices via bf16 MFMA 16x16x32, per-matmul scale 2^-7 (exact);
//   A-fragments loaded DIRECTLY global->reg (no LDS at all).
// Phase 2: per-batch fold of 16 chunk matrices. Phase 3: deterministic reduce
//   (+ compile-time log-correction 496*7*ln2).

#define S_LEN 512
#define BATCH 128
#define T 48
#define TT 2304
#define START_TAG 46
#define END_TAG 47

#define CHUNK 32
#define NCHUNK 16
#define NTASK (NCHUNK * BATCH)       // 2048
#define P1_WAVES 4
#define P1_THREADS 256
#define P1_BLOCKS (NTASK / P1_WAVES) // 512
#define SIGMA 0.0078125f             // 2^-7

typedef float f32x4 __attribute__((ext_vector_type(4)));
typedef short bf16x8 __attribute__((ext_vector_type(8)));

__device__ __forceinline__ short f2bf(float x) {  // RTNE f32->bf16 bits
  unsigned u = __float_as_uint(x);
  u = (u + 0x7fffu + ((u >> 16) & 1u)) >> 16;
  return (short)u;
}

// ---------------- Phase 1: per-chunk matrix product, register-direct ----------------
__global__ __launch_bounds__(P1_THREADS, 3) void crf_chunk(
    const float* __restrict__ scores, const int* __restrict__ target,
    const int* __restrict__ mask, float* __restrict__ Rbuf,
    float* __restrict__ tgbuf)
{
  const int t = threadIdx.x;
  const int lane = t & 63;
  const int wid = t >> 6;
  const int g = lane >> 4;    // 0..3
  const int c15 = lane & 15;  // 0..15

  const int task = blockIdx.x * P1_WAVES + wid;
  const int b = task & (BATCH - 1);
  const int cIdx = task >> 7;
  const int s0 = cIdx * CHUNK;

  // mask (lanes 0..31) / target (lanes 32..63) for this chunk, one reg
  int mt;
  {
    int sl = s0 + (lane & 31);
    mt = (lane < 32) ? mask[(size_t)sl * BATCH + b]
                     : target[(size_t)sl * BATCH + b];
  }

  // tg gather: lane k (k<32) loads scores[s0+k][b][tgt_k] -- all steps CONCURRENT
  float tg = 0.f;
  {
    int tgt_l = __shfl(mt, 32 + (lane & 31), 64);
    if (lane < CHUNK && mt)  // lane<32: mt == mask[s0+lane]
      tg = scores[((size_t)(s0 + lane) * BATCH + b) * TT + tgt_l];
  }

  const float* sb0 = scores + ((size_t)s0 * BATCH + b) * TT;

  // ---- init B = E_{s0}^T  (B[kk][col] = E[col][kk]); identity if s0==0 or masked
  const int msk0 = __shfl(mt, 0, 64);
  const bool id0 = (s0 == 0) || (msk0 == 0);
  bf16x8 Bf[2][3];
#pragma unroll
  for (int tk = 0; tk < 2; ++tk)
#pragma unroll
    for (int tj = 0; tj < 3; ++tj) {
      bf16x8 bv;
#pragma unroll
      for (int i = 0; i < 8; ++i) {
        int kk = 32 * tk + 8 * g + i;
        int col = 16 * tj + c15;
        float val = 0.f;
        if (kk < T)
          val = id0 ? ((kk == col) ? 1.f : 0.f)
                    : __expf(sb0[(size_t)col * T + kk]);
        bv[i] = f2bf(val);
      }
      Bf[tk][tj] = bv;
    }

  f32x4 Cf[3][3];
  const f32x4 zz = {0.f, 0.f, 0.f, 0.f};
  const float* sE = sb0;

#pragma unroll 1
  for (int k = 1; k < CHUNK; ++k) {
    sE += (size_t)BATCH * TT;
    const int msk = __shfl(mt, k, 64);
    const bool ident = (msk == 0);

    // ---- tk=0 half: rows kk = 8g+i (always < 32 < 48, in-bounds)
    const float* p0 = sE + (size_t)(8 * g) * T + c15;
    float eb[24];
#pragma unroll
    for (int ti = 0; ti < 3; ++ti)
#pragma unroll
      for (int i = 0; i < 8; ++i)
        eb[ti * 8 + i] = p0[(size_t)i * T + ti * 16];

    bf16x8 A0[3];
#pragma unroll
    for (int ti = 0; ti < 3; ++ti) {
      bf16x8 av;
#pragma unroll
      for (int i = 0; i < 8; ++i) {
        float v = ident ? (((8 * g + i) == (16 * ti + c15)) ? SIGMA : 0.f)
                        : __expf(eb[ti * 8 + i]) * SIGMA;
        av[i] = f2bf(v);
      }
      A0[ti] = av;
    }
#pragma unroll
    for (int ti = 0; ti < 3; ++ti)
#pragma unroll
      for (int tj = 0; tj < 3; ++tj)
        Cf[ti][tj] = __builtin_amdgcn_mfma_f32_16x16x32_bf16(A0[ti], Bf[0][tj], zz, 0, 0, 0);

    // ---- tk=1 half: rows kk = 32+8g+i; valid only g<2 (kk<48); clamp addr for g>=2
    const float* p1 = sE + (size_t)((g < 2) ? (32 + 8 * g) : 0) * T + c15;
#pragma unroll
    for (int ti = 0; ti < 3; ++ti)
#pragma unroll
      for (int i = 0; i < 8; ++i)
        eb[ti * 8 + i] = p1[(size_t)i * T + ti * 16];

    bf16x8 A1[3];
#pragma unroll
    for (int ti = 0; ti < 3; ++ti) {
      bf16x8 av;
#pragma unroll
      for (int i = 0; i < 8; ++i) {
        int kk = 32 + 8 * g + i;
        float v = 0.f;
        if (kk < T)
          v = ident ? ((kk == (16 * ti + c15)) ? SIGMA : 0.f)
                    : __expf(eb[ti * 8 + i]) * SIGMA;
        av[i] = f2bf(v);
      }
      A1[ti] = av;
    }
#pragma unroll
    for (int ti = 0; ti < 3; ++ti)
#pragma unroll
      for (int tj = 0; tj < 3; ++tj)
        Cf[ti][tj] = __builtin_amdgcn_mfma_f32_16x16x32_bf16(A1[ti], Bf[1][tj], Cf[ti][tj], 0, 0, 0);

    // ---- recycle C -> next B, register-only shuffles (verbatim proven mapping)
#pragma unroll
    for (int tj = 0; tj < 3; ++tj) {
      bf16x8 b0, b1;
      int srcLo = ((g & 1) << 5) + c15;
      int srcHi = srcLo + 16;
#pragma unroll
      for (int i = 0; i < 8; ++i) {
        int r = i & 3;
        int src = (i < 4) ? srcLo : srcHi;
        float a0 = __shfl(Cf[0][tj][r], src, 64);
        float a1 = __shfl(Cf[1][tj][r], src, 64);
        b0[i] = f2bf((g >> 1) ? a1 : a0);
        float a2 = __shfl(Cf[2][tj][r], src, 64);
        b1[i] = f2bf((g >> 1) ? 0.f : a2);
      }
      Bf[0][tj] = b0;
      Bf[1][tj] = b1;
    }
  }

  // write chunk product R^T (48x48, stored row-major [j][i])
  float* outp = Rbuf + (size_t)((size_t)cIdx * BATCH + b) * TT;
#pragma unroll
  for (int ti = 0; ti < 3; ++ti)
#pragma unroll
    for (int tj = 0; tj < 3; ++tj)
#pragma unroll
      for (int r = 0; r < 4; ++r) {
        int j = 16 * ti + 4 * g + r;
        int icol = 16 * tj + c15;
        outp[j * T + icol] = Cf[ti][tj][r];
      }

  // reduce tg across lanes (lanes >= CHUNK hold 0)
#pragma unroll
  for (int d = 1; d < 64; d <<= 1) tg += __shfl_xor(tg, d, 64);
  if (lane == 0) tgbuf[task] = tg;
}

// ---------------- Phase 2: per-batch fold over 16 chunk matrices ----------------
__global__ __launch_bounds__(64) void crf_fold(
    const float* __restrict__ scores, const float* __restrict__ Rbuf,
    float* __restrict__ pend)
{
  __shared__ __align__(16) float e[T];
  const int b = blockIdx.x;
  const int j = threadIdx.x & 63;
  const int jr = (j < T) ? j : (T - 1);
  float p = (j < T) ? scores[(size_t)b * TT + START_TAG * T + j] : -1e30f;

  float4 bufA[12], bufB[12];
  {
    const float4* rA = (const float4*)(Rbuf + ((size_t)0 * BATCH + b) * TT + (size_t)jr * T);
#pragma unroll
    for (int q = 0; q < 12; ++q) bufA[q] = rA[q];
  }

#pragma unroll 1
  for (int c = 0; c < NCHUNK; c += 2) {
    const float4* rB = (const float4*)(Rbuf + ((size_t)(c + 1) * BATCH + b) * TT + (size_t)jr * T);
#pragma unroll
    for (int q = 0; q < 12; ++q) bufB[q] = rB[q];

    { // step c (bufA)
      float sh = __shfl(p, 0, 64);
      float ev = __expf(p - sh);
      if (j < T) e[j] = ev;
      asm volatile("s_waitcnt lgkmcnt(0)" ::: "memory");
      float acc = 0.f;
#pragma unroll
      for (int q = 0; q < 12; ++q) {
        float4 ef = ((const float4*)e)[q];
        acc += ef.x * bufA[q].x; acc += ef.y * bufA[q].y;
        acc += ef.z * bufA[q].z; acc += ef.w * bufA[q].w;
      }
      p = sh + __logf(acc);
    }
    if (c + 2 < NCHUNK) {
      const float4* rA = (const float4*)(Rbuf + ((size_t)(c + 2) * BATCH + b) * TT + (size_t)jr * T);
#pragma unroll
      for (int q = 0; q < 12; ++q) bufA[q] = rA[q];
    }
    { // step c+1 (bufB)
      float sh = __shfl(p, 0, 64);
      float ev = __expf(p - sh);
      if (j < T) e[j] = ev;
      asm volatile("s_waitcnt lgkmcnt(0)" ::: "memory");
      float acc = 0.f;
#pragma unroll
      for (int q = 0; q < 12; ++q) {
        float4 ef = ((const float4*)e)[q];
        acc += ef.x * bufB[q].x; acc += ef.y * bufB[q].y;
        acc += ef.z * bufB[q].z; acc += ef.w * bufB[q].w;
      }
      p = sh + __logf(acc);
    }
  }
  if (j == END_TAG) pend[b] = p;
}

// ---------------- Phase 3: deterministic reduce ----------------
__global__ void crf_final(const float* __restrict__ pend, const float* __restrict__ tgbuf,
                          float* __restrict__ out)
{
  __shared__ float sp[256], st2[256];
  int t = threadIdx.x;
  float ps = (t < BATCH) ? pend[t] : 0.f;
  float ts = 0.f;
  for (int q = t; q < NTASK; q += 256) ts += tgbuf[q];
  sp[t] = ps; st2[t] = ts;
  __syncthreads();
  for (int off = 128; off > 0; off >>= 1) {
    if (t < off) { sp[t] += sp[t + off]; st2[t] += st2[t + off]; }
    __syncthreads();
  }
  if (t == 0) {
    // 16 chunks * 31 matmuls * 7*ln2 (exact 2^-7 per-matmul scale)
    const float corr = 496.0f * 4.852030263919617f;
    out[0] = (sp[0] - st2[0]) / (float)BATCH + corr;
  }
}

// ---------------- Fallback (proven round-1 scan) for small ws ----------------
__global__ __launch_bounds__(512) void fb_scan(
    const float* __restrict__ scores, const int* __restrict__ target,
    const int* __restrict__ mask, float* __restrict__ ws)
{
  __shared__ float tile[2][TT];
  __shared__ float p[T];
  __shared__ float red_m[8][T];
  __shared__ float red_s[8][T];
  __shared__ int lmask[S_LEN];
  __shared__ int ltgt[S_LEN];

  const int b = blockIdx.x;
  const int t = threadIdx.x;
  const int j = t & 63;
  const int ic = t >> 6;
  const bool valid = (j < T);

  lmask[t] = mask[(size_t)t * BATCH + b];
  ltgt[t] = target[(size_t)t * BATCH + b];
  {
    const float4* src = (const float4*)(scores + (size_t)b * TT);
    float4 r0 = src[t]; float4 r1;
    if (t < 64) r1 = src[512 + t];
    float4* dst = (float4*)tile[0];
    dst[t] = r0;
    if (t < 64) dst[512 + t] = r1;
  }
  __syncthreads();
  float tg_local = 0.0f;
  for (int s = 0; s < S_LEN; ++s) {
    const int buf = s & 1;
    float4 r0, r1;
    if (s + 1 < S_LEN) {
      const float4* src = (const float4*)(scores + ((size_t)(s + 1) * BATCH + b) * TT);
      r0 = src[t];
      if (t < 64) r1 = src[512 + t];
    }
    if (s == 0) {
      if (t < T) p[t] = tile[0][START_TAG * T + t];
      if (t == 0 && lmask[0]) tg_local += tile[0][ltgt[0]];
    } else {
      if (valid) {
        const int i0 = ic * 6;
        float x[6]; float m = -1e30f;
#pragma unroll
        for (int k = 0; k < 6; ++k) {
          x[k] = tile[buf][(i0 + k) * T + j] + p[i0 + k];
          m = fmaxf(m, x[k]);
        }
        float sum = 0.0f;
#pragma unroll
        for (int k = 0; k < 6; ++k) sum += __expf(x[k] - m);
        red_m[ic][j] = m; red_s[ic][j] = sum;
      }
      if (t == 0 && lmask[s]) tg_local += tile[buf][ltgt[s]];
    }
    __syncthreads();
    if (s > 0 && t < T) {
      float M = red_m[0][t];
#pragma unroll
      for (int g2 = 1; g2 < 8; ++g2) M = fmaxf(M, red_m[g2][t]);
      float Ssum = 0.0f;
#pragma unroll
      for (int g2 = 0; g2 < 8; ++g2) Ssum += red_s[g2][t] * __expf(red_m[g2][t] - M);
      float cur = M + __logf(Ssum);
      if (lmask[s]) p[t] = cur;
    }
    if (s + 1 < S_LEN) {
      float4* dst = (float4*)tile[buf ^ 1];
      dst[t] = r0;
      if (t < 64) dst[512 + t] = r1;
    }
    __syncthreads();
  }
  if (t == 0) ws[b] = p[END_TAG] - tg_local;
}

__global__ void fb_reduce(const float* __restrict__ ws, float* __restrict__ out)
{
  __shared__ float sh[BATCH];
  const int t = threadIdx.x;
  if (t < BATCH) sh[t] = ws[t];
  __syncthreads();
  if (t == 0) {
    float s = 0.0f;
    for (int k = 0; k < BATCH; ++k) s += sh[k];
    out[0] = s / (float)BATCH;
  }
}

extern "C" void kernel_launch(void* const* d_in, const int* in_sizes, int n_in,
                              void* d_out, int out_size, void* d_ws, size_t ws_size,
                              hipStream_t stream)
{
  const float* scores = (const float*)d_in[0];
  const int* target = (const int*)d_in[1];
  const int* mask = (const int*)d_in[2];
  float* out = (float*)d_out;

  const size_t RB_FLOATS = (size_t)NTASK * TT;
  const size_t need = RB_FLOATS * 4 + (size_t)NTASK * 4 + (size_t)BATCH * 4;

  if (ws_size >= need) {
    float* Rbuf = (float*)d_ws;
    float* tgbuf = Rbuf + RB_FLOATS;
    float* pend = tgbuf + NTASK;
    crf_chunk<<<P1_BLOCKS, P1_THREADS, 0, stream>>>(scores, target, mask, Rbuf, tgbuf);
    crf_fold<<<BATCH, 64, 0, stream>>>(scores, Rbuf, pend);
    crf_final<<<1, 256, 0, stream>>>(pend, tgbuf, out);
  } else {
    float* ws = (float*)d_ws;
    fb_scan<<<BATCH, 512, 0, stream>>>(scores, target, mask, ws);
    fb_reduce<<<1, 128, 0, stream>>>(ws, out);
  }
}

// Round 6
// 130.695 us; speedup vs baseline: 3.0521x; 1.2484x over previous
//
#include <hip/hip_runtime.h>

// CRF loss forward, chunked log-semiring matrix-product formulation (register-direct v2).
// scores (512,128,48,48) f32, target (512,128) int32, mask (512,128) int32 -> scalar f32
//
// Phase 1: 2048 independent waves; wave (c,b) computes prod of 32 exp-space
//   transition matrices. K=48 split as 32 (mfma 16x16x32) + 16 (mfma 16x16x16):
//   all loads/exps lane-valid, and the K16 recycle is shuffle-free (B16 k-layout
//   == C/D row layout). Per-matmul scale 2^-7 (exact); correction const at end.
//   Raw f32 inputs double-buffered in registers (prefetch one step ahead).
// Phase 2: per-batch fold of 16 chunk matrices. Phase 3: deterministic reduce.

#define S_LEN 512
#define BATCH 128
#define T 48
#define TT 2304
#define START_TAG 46
#define END_TAG 47

#define CHUNK 32
#define NCHUNK 16
#define NTASK (NCHUNK * BATCH)       // 2048
#define P1_WAVES 4
#define P1_THREADS 256
#define P1_BLOCKS (NTASK / P1_WAVES) // 512
#define SIGMA 0.0078125f             // 2^-7

typedef float f32x4 __attribute__((ext_vector_type(4)));
typedef short bf16x8 __attribute__((ext_vector_type(8)));
typedef short bf16x4 __attribute__((ext_vector_type(4)));

__device__ __forceinline__ short f2bf(float x) {  // RTNE f32->bf16 bits
  unsigned u = __float_as_uint(x);
  u = (u + 0x7fffu + ((u >> 16) & 1u)) >> 16;
  return (short)u;
}

#if __has_builtin(__builtin_amdgcn_exp2f)
#define EXPS(x) __builtin_amdgcn_exp2f(fmaf((x), 1.44269504089f, -7.0f))
#define EXP1(x) __builtin_amdgcn_exp2f((x) * 1.44269504089f)
#else
#define EXPS(x) (__expf(x) * SIGMA)
#define EXP1(x) __expf(x)
#endif

#if __has_builtin(__builtin_amdgcn_mfma_f32_16x16x16bf16_1k)
#define MFMA16(a, b, c) __builtin_amdgcn_mfma_f32_16x16x16bf16_1k((a), (b), (c), 0, 0, 0)
#else
static __device__ __forceinline__ f32x4 mfma16_asm(bf16x4 a, bf16x4 b, f32x4 c) {
  f32x4 d;
  asm volatile("v_mfma_f32_16x16x16_bf16 %0, %1, %2, %3\n\ts_nop 7"
               : "=v"(d) : "v"(a), "v"(b), "v"(c));
  return d;
}
#define MFMA16(a, b, c) mfma16_asm((a), (b), (c))
#endif

struct Raw { float r24[24]; float r12[12]; };

// load next matrix's A-fragment raw f32 values (36/lane, fully coalesced 64B segs)
#define CRF_LOAD(RW, PE) do {                                                  \
  const float* q0_ = (PE) + (size_t)(8 * g) * T + c15;                         \
  _Pragma("unroll") for (int ti = 0; ti < 3; ++ti)                             \
    _Pragma("unroll") for (int i = 0; i < 8; ++i)                              \
      (RW).r24[ti * 8 + i] = q0_[(size_t)i * T + 16 * ti];                     \
  const float* q1_ = (PE) + (size_t)(32 + 4 * g) * T + c15;                    \
  _Pragma("unroll") for (int ti = 0; ti < 3; ++ti)                             \
    _Pragma("unroll") for (int i = 0; i < 4; ++i)                              \
      (RW).r12[ti * 4 + i] = q1_[(size_t)i * T + 16 * ti];                     \
} while (0)

// one product step: A = sigma*E_k^T (or sigma*I if masked); Cf = A32.B32 + A16.B16;
// then recycle Cf -> (Bf32, Bf16) for the next step.
#define CRF_STEP(RW, KK, RECYC) do {                                           \
  const int msk_ = __shfl(mt, (KK), 64);                                       \
  const bool id_ = (msk_ == 0);                                                \
  bf16x8 A32_[3]; bf16x4 A16_[3];                                              \
  _Pragma("unroll") for (int ti = 0; ti < 3; ++ti) {                           \
    bf16x8 av_;                                                                \
    _Pragma("unroll") for (int i = 0; i < 8; ++i) {                            \
      float v_ = id_ ? (((8 * g + i) == (16 * ti + c15)) ? SIGMA : 0.f)        \
                     : EXPS((RW).r24[ti * 8 + i]);                             \
      av_[i] = f2bf(v_);                                                       \
    }                                                                          \
    A32_[ti] = av_;                                                            \
    bf16x4 aw_;                                                                \
    _Pragma("unroll") for (int i = 0; i < 4; ++i) {                            \
      float v_ = id_ ? (((32 + 4 * g + i) == (16 * ti + c15)) ? SIGMA : 0.f)   \
                     : EXPS((RW).r12[ti * 4 + i]);                             \
      aw_[i] = f2bf(v_);                                                       \
    }                                                                          \
    A16_[ti] = aw_;                                                            \
  }                                                                            \
  _Pragma("unroll") for (int ti = 0; ti < 3; ++ti)                             \
    _Pragma("unroll") for (int tj = 0; tj < 3; ++tj)                           \
      Cf[ti][tj] = __builtin_amdgcn_mfma_f32_16x16x32_bf16(A32_[ti], Bf32[tj], zz, 0, 0, 0); \
  _Pragma("unroll") for (int ti = 0; ti < 3; ++ti)                             \
    _Pragma("unroll") for (int tj = 0; tj < 3; ++tj)                           \
      Cf[ti][tj] = MFMA16(A16_[ti], Bf16[tj], Cf[ti][tj]);                     \
  if (RECYC) {                                                                 \
    _Pragma("unroll") for (int tj = 0; tj < 3; ++tj) {                         \
      bf16x8 b0_; bf16x4 b1_;                                                  \
      const int sLo_ = ((g & 1) << 5) + c15;                                   \
      _Pragma("unroll") for (int i = 0; i < 8; ++i) {                          \
        const int r_ = i & 3;                                                  \
        const int s_ = sLo_ + ((i & 4) ? 16 : 0);                              \
        float a0_ = __shfl(Cf[0][tj][r_], s_, 64);                             \
        float a1_ = __shfl(Cf[1][tj][r_], s_, 64);                             \
        b0_[i] = f2bf((g >> 1) ? a1_ : a0_);                                   \
      }                                                                        \
      _Pragma("unroll") for (int i = 0; i < 4; ++i) b1_[i] = f2bf(Cf[2][tj][i]); \
      Bf32[tj] = b0_; Bf16[tj] = b1_;                                          \
    }                                                                          \
  }                                                                            \
} while (0)

// ---------------- Phase 1: per-chunk matrix product ----------------
__global__ __launch_bounds__(P1_THREADS, 2) void crf_chunk(
    const float* __restrict__ scores, const int* __restrict__ target,
    const int* __restrict__ mask, float* __restrict__ Rbuf,
    float* __restrict__ tgbuf)
{
  const int t = threadIdx.x;
  const int lane = t & 63;
  const int wid = t >> 6;
  const int g = lane >> 4;    // 0..3
  const int c15 = lane & 15;  // 0..15

  const int task = blockIdx.x * P1_WAVES + wid;
  const int b = task & (BATCH - 1);
  const int cIdx = task >> 7;
  const int s0 = cIdx * CHUNK;

  // mask (lanes 0..31) / target (lanes 32..63) for this chunk, one reg
  int mt;
  {
    int sl = s0 + (lane & 31);
    mt = (lane < 32) ? mask[(size_t)sl * BATCH + b]
                     : target[(size_t)sl * BATCH + b];
  }

  // tg gather: lane k (k<32) loads scores[s0+k][b][tgt_k] -- all steps CONCURRENT
  float tg = 0.f;
  {
    int tgt_l = __shfl(mt, 32 + (lane & 31), 64);
    if (lane < CHUNK && mt)  // lane<32: mt == mask[s0+lane]
      tg = scores[((size_t)(s0 + lane) * BATCH + b) * TT + tgt_l];
  }

  const float* sb0 = scores + ((size_t)s0 * BATCH + b) * TT;

  // prefetch raws for k=1 as early as possible (overlaps the scattered B-init)
  Raw rA, rB;
  CRF_LOAD(rA, sb0 + (size_t)BATCH * TT);

  // ---- init B = E_{s0}^T; identity if s0==0 or masked.
  // Bf32: kk=8g+i (0..31); Bf16: kk=32+4g+i (32..47); col = 16tj+c15.
  const int msk0 = __shfl(mt, 0, 64);
  const bool id0 = (s0 == 0) || (msk0 == 0);
  bf16x8 Bf32[3];
  bf16x4 Bf16[3];
#pragma unroll
  for (int tj = 0; tj < 3; ++tj) {
    const int col = 16 * tj + c15;
    bf16x8 bv;
#pragma unroll
    for (int i = 0; i < 8; ++i) {
      int kk = 8 * g + i;
      float val = id0 ? ((kk == col) ? 1.f : 0.f)
                      : EXP1(sb0[(size_t)col * T + kk]);
      bv[i] = f2bf(val);
    }
    Bf32[tj] = bv;
    bf16x4 bw;
#pragma unroll
    for (int i = 0; i < 4; ++i) {
      int kk = 32 + 4 * g + i;
      float val = id0 ? ((kk == col) ? 1.f : 0.f)
                      : EXP1(sb0[(size_t)col * T + kk]);
      bw[i] = f2bf(val);
    }
    Bf16[tj] = bw;
  }

  f32x4 Cf[3][3];
  const f32x4 zz = {0.f, 0.f, 0.f, 0.f};

  // main loop, software-pipelined x2: load(k+1) | step(k) | load(k+2) | step(k+1)
  int k = 1;
#pragma unroll 1
  for (; k + 1 < CHUNK; k += 2) {
    CRF_LOAD(rB, sb0 + (size_t)(k + 1) * BATCH * TT);
    CRF_STEP(rA, k, 1);
    CRF_LOAD(rA, sb0 + (size_t)(k + 2) * BATCH * TT);
    CRF_STEP(rB, k + 1, 1);
  }
  CRF_STEP(rA, k, 0);  // k == CHUNK-1, no recycle needed

  // write chunk product R^T (48x48, stored row-major [j][i])
  float* outp = Rbuf + (size_t)((size_t)cIdx * BATCH + b) * TT;
#pragma unroll
  for (int ti = 0; ti < 3; ++ti)
#pragma unroll
    for (int tj = 0; tj < 3; ++tj)
#pragma unroll
      for (int r = 0; r < 4; ++r) {
        int j = 16 * ti + 4 * g + r;
        int icol = 16 * tj + c15;
        outp[j * T + icol] = Cf[ti][tj][r];
      }

  // reduce tg across lanes (lanes >= CHUNK hold 0)
#pragma unroll
  for (int d = 1; d < 64; d <<= 1) tg += __shfl_xor(tg, d, 64);
  if (lane == 0) tgbuf[task] = tg;
}

// ---------------- Phase 2: per-batch fold over 16 chunk matrices ----------------
__global__ __launch_bounds__(64) void crf_fold(
    const float* __restrict__ scores, const float* __restrict__ Rbuf,
    float* __restrict__ pend)
{
  __shared__ __align__(16) float e[T];
  const int b = blockIdx.x;
  const int j = threadIdx.x & 63;
  const int jr = (j < T) ? j : (T - 1);
  float p = (j < T) ? scores[(size_t)b * TT + START_TAG * T + j] : -1e30f;

  float4 bufA[12], bufB[12];
  {
    const float4* rA = (const float4*)(Rbuf + ((size_t)0 * BATCH + b) * TT + (size_t)jr * T);
#pragma unroll
    for (int q = 0; q < 12; ++q) bufA[q] = rA[q];
  }

#pragma unroll 1
  for (int c = 0; c < NCHUNK; c += 2) {
    const float4* rB = (const float4*)(Rbuf + ((size_t)(c + 1) * BATCH + b) * TT + (size_t)jr * T);
#pragma unroll
    for (int q = 0; q < 12; ++q) bufB[q] = rB[q];

    { // step c (bufA)
      float sh = __shfl(p, 0, 64);
      float ev = __expf(p - sh);
      if (j < T) e[j] = ev;
      asm volatile("s_waitcnt lgkmcnt(0)" ::: "memory");
      float acc = 0.f;
#pragma unroll
      for (int q = 0; q < 12; ++q) {
        float4 ef = ((const float4*)e)[q];
        acc += ef.x * bufA[q].x; acc += ef.y * bufA[q].y;
        acc += ef.z * bufA[q].z; acc += ef.w * bufA[q].w;
      }
      p = sh + __logf(acc);
    }
    if (c + 2 < NCHUNK) {
      const float4* rA = (const float4*)(Rbuf + ((size_t)(c + 2) * BATCH + b) * TT + (size_t)jr * T);
#pragma unroll
      for (int q = 0; q < 12; ++q) bufA[q] = rA[q];
    }
    { // step c+1 (bufB)
      float sh = __shfl(p, 0, 64);
      float ev = __expf(p - sh);
      if (j < T) e[j] = ev;
      asm volatile("s_waitcnt lgkmcnt(0)" ::: "memory");
      float acc = 0.f;
#pragma unroll
      for (int q = 0; q < 12; ++q) {
        float4 ef = ((const float4*)e)[q];
        acc += ef.x * bufB[q].x; acc += ef.y * bufB[q].y;
        acc += ef.z * bufB[q].z; acc += ef.w * bufB[q].w;
      }
      p = sh + __logf(acc);
    }
  }
  if (j == END_TAG) pend[b] = p;
}

// ---------------- Phase 3: deterministic reduce ----------------
__global__ void crf_final(const float* __restrict__ pend, const float* __restrict__ tgbuf,
                          float* __restrict__ out)
{
  __shared__ float sp[256], st2[256];
  int t = threadIdx.x;
  float ps = (t < BATCH) ? pend[t] : 0.f;
  float ts = 0.f;
  for (int q = t; q < NTASK; q += 256) ts += tgbuf[q];
  sp[t] = ps; st2[t] = ts;
  __syncthreads();
  for (int off = 128; off > 0; off >>= 1) {
    if (t < off) { sp[t] += sp[t + off]; st2[t] += st2[t + off]; }
    __syncthreads();
  }
  if (t == 0) {
    // 16 chunks * 31 matmuls * 7*ln2 (exact 2^-7 per-matmul scale)
    const float corr = 496.0f * 4.852030263919617f;
    out[0] = (sp[0] - st2[0]) / (float)BATCH + corr;
  }
}

// ---------------- Fallback (proven round-1 scan) for small ws ----------------
__global__ __launch_bounds__(512) void fb_scan(
    const float* __restrict__ scores, const int* __restrict__ target,
    const int* __restrict__ mask, float* __restrict__ ws)
{
  __shared__ float tile[2][TT];
  __shared__ float p[T];
  __shared__ float red_m[8][T];
  __shared__ float red_s[8][T];
  __shared__ int lmask[S_LEN];
  __shared__ int ltgt[S_LEN];

  const int b = blockIdx.x;
  const int t = threadIdx.x;
  const int j = t & 63;
  const int ic = t >> 6;
  const bool valid = (j < T);

  lmask[t] = mask[(size_t)t * BATCH + b];
  ltgt[t] = target[(size_t)t * BATCH + b];
  {
    const float4* src = (const float4*)(scores + (size_t)b * TT);
    float4 r0 = src[t]; float4 r1;
    if (t < 64) r1 = src[512 + t];
    float4* dst = (float4*)tile[0];
    dst[t] = r0;
    if (t < 64) dst[512 + t] = r1;
  }
  __syncthreads();
  float tg_local = 0.0f;
  for (int s = 0; s < S_LEN; ++s) {
    const int buf = s & 1;
    float4 r0, r1;
    if (s + 1 < S_LEN) {
      const float4* src = (const float4*)(scores + ((size_t)(s + 1) * BATCH + b) * TT);
      r0 = src[t];
      if (t < 64) r1 = src[512 + t];
    }
    if (s == 0) {
      if (t < T) p[t] = tile[0][START_TAG * T + t];
      if (t == 0 && lmask[0]) tg_local += tile[0][ltgt[0]];
    } else {
      if (valid) {
        const int i0 = ic * 6;
        float x[6]; float m = -1e30f;
#pragma unroll
        for (int kq = 0; kq < 6; ++kq) {
          x[kq] = tile[buf][(i0 + kq) * T + j] + p[i0 + kq];
          m = fmaxf(m, x[kq]);
        }
        float sum = 0.0f;
#pragma unroll
        for (int kq = 0; kq < 6; ++kq) sum += __expf(x[kq] - m);
        red_m[ic][j] = m; red_s[ic][j] = sum;
      }
      if (t == 0 && lmask[s]) tg_local += tile[buf][ltgt[s]];
    }
    __syncthreads();
    if (s > 0 && t < T) {
      float M = red_m[0][t];
#pragma unroll
      for (int g2 = 1; g2 < 8; ++g2) M = fmaxf(M, red_m[g2][t]);
      float Ssum = 0.0f;
#pragma unroll
      for (int g2 = 0; g2 < 8; ++g2) Ssum += red_s[g2][t] * __expf(red_m[g2][t] - M);
      float cur = M + __logf(Ssum);
      if (lmask[s]) p[t] = cur;
    }
    if (s + 1 < S_LEN) {
      float4* dst = (float4*)tile[buf ^ 1];
      dst[t] = r0;
      if (t < 64) dst[512 + t] = r1;
    }
    __syncthreads();
  }
  if (t == 0) ws[b] = p[END_TAG] - tg_local;
}

__global__ void fb_reduce(const float* __restrict__ ws, float* __restrict__ out)
{
  __shared__ float sh[BATCH];
  const int t = threadIdx.x;
  if (t < BATCH) sh[t] = ws[t];
  __syncthreads();
  if (t == 0) {
    float s = 0.0f;
    for (int k = 0; k < BATCH; ++k) s += sh[k];
    out[0] = s / (float)BATCH;
  }
}

extern "C" void kernel_launch(void* const* d_in, const int* in_sizes, int n_in,
                              void* d_out, int out_size, void* d_ws, size_t ws_size,
                              hipStream_t stream)
{
  const float* scores = (const float*)d_in[0];
  const int* target = (const int*)d_in[1];
  const int* mask = (const int*)d_in[2];
  float* out = (float*)d_out;

  const size_t RB_FLOATS = (size_t)NTASK * TT;
  const size_t need = RB_FLOATS * 4 + (size_t)NTASK * 4 + (size_t)BATCH * 4;

  if (ws_size >= need) {
    float* Rbuf = (float*)d_ws;
    float* tgbuf = Rbuf + RB_FLOATS;
    float* pend = tgbuf + NTASK;
    crf_chunk<<<P1_BLOCKS, P1_THREADS, 0, stream>>>(scores, target, mask, Rbuf, tgbuf);
    crf_fold<<<BATCH, 64, 0, stream>>>(scores, Rbuf, pend);
    crf_final<<<1, 256, 0, stream>>>(pend, tgbuf, out);
  } else {
    float* ws = (float*)d_ws;
    fb_scan<<<BATCH, 512, 0, stream>>>(scores, target, mask, ws);
    fb_reduce<<<1, 128, 0, stream>>>(ws, out);
  }
}

// Round 7
// 121.472 us; speedup vs baseline: 3.2838x; 1.0759x over previous
//
#include <hip/hip_runtime.h>

// CRF loss forward, chunked log-semiring matrix-product formulation (register-direct v3).
// scores (512,128,48,48) f32, target (512,128) int32, mask (512,128) int32 -> scalar f32
//
// Phase 1: 2048 independent waves; wave (c,b) computes prod of 32 exp-space
//   transition matrices starting from an EXACT identity B (no scattered B-init
//   read). K=48 split as 32 (mfma 16x16x32) + 16 (mfma 16x16x16). Per-step
//   scale 2^-7 exact (incl. identity steps) -> correction 512*7*ln2.
//   Chunk products stored bf16 (halves scratch traffic).
// Phase 2: per-batch fold of 16 bf16 chunk matrices. Phase 3: deterministic reduce.

#define S_LEN 512
#define BATCH 128
#define T 48
#define TT 2304
#define START_TAG 46
#define END_TAG 47

#define CHUNK 32
#define NCHUNK 16
#define NTASK (NCHUNK * BATCH)       // 2048
#define P1_WAVES 4
#define P1_THREADS 256
#define P1_BLOCKS (NTASK / P1_WAVES) // 512
#define SIGMA 0.0078125f             // 2^-7

typedef float f32x4 __attribute__((ext_vector_type(4)));
typedef short bf16x8 __attribute__((ext_vector_type(8)));
typedef short bf16x4 __attribute__((ext_vector_type(4)));

__device__ __forceinline__ short f2bf(float x) {  // RTNE f32->bf16 bits
  unsigned u = __float_as_uint(x);
  u = (u + 0x7fffu + ((u >> 16) & 1u)) >> 16;
  return (short)u;
}

#if __has_builtin(__builtin_amdgcn_exp2f)
#define EXPS(x) __builtin_amdgcn_exp2f(fmaf((x), 1.44269504089f, -7.0f))
#else
#define EXPS(x) (__expf(x) * SIGMA)
#endif

#if __has_builtin(__builtin_amdgcn_mfma_f32_16x16x16bf16_1k)
#define MFMA16(a, b, c) __builtin_amdgcn_mfma_f32_16x16x16bf16_1k((a), (b), (c), 0, 0, 0)
#else
static __device__ __forceinline__ f32x4 mfma16_asm(bf16x4 a, bf16x4 b, f32x4 c) {
  f32x4 d;
  asm volatile("v_mfma_f32_16x16x16_bf16 %0, %1, %2, %3\n\ts_nop 7"
               : "=v"(d) : "v"(a), "v"(b), "v"(c));
  return d;
}
#define MFMA16(a, b, c) mfma16_asm((a), (b), (c))
#endif

struct Raw { float r24[24]; float r12[12]; };

// load matrix k's A-fragment raw f32 values (36/lane, coalesced 64B segments)
#define CRF_LOAD(RW, PE) do {                                                  \
  const float* q0_ = (PE) + (size_t)(8 * g) * T + c15;                         \
  _Pragma("unroll") for (int ti = 0; ti < 3; ++ti)                             \
    _Pragma("unroll") for (int i = 0; i < 8; ++i)                              \
      (RW).r24[ti * 8 + i] = q0_[(size_t)i * T + 16 * ti];                     \
  const float* q1_ = (PE) + (size_t)(32 + 4 * g) * T + c15;                    \
  _Pragma("unroll") for (int ti = 0; ti < 3; ++ti)                             \
    _Pragma("unroll") for (int i = 0; i < 4; ++i)                              \
      (RW).r12[ti * 4 + i] = q1_[(size_t)i * T + 16 * ti];                     \
} while (0)

// one product step: A = sigma*E^T (or sigma*I if masked or global step 0);
// Cf = A32.B32 + A16.B16; then recycle Cf -> (Bf32, Bf16).
#define CRF_STEP(RW, KK, RECYC) do {                                           \
  const int msk_ = __shfl(mt, (KK), 64);                                       \
  const bool id_ = (msk_ == 0) || ((s0 == 0) && ((KK) == 0));                  \
  bf16x8 A32_[3]; bf16x4 A16_[3];                                              \
  _Pragma("unroll") for (int ti = 0; ti < 3; ++ti) {                           \
    bf16x8 av_;                                                                \
    _Pragma("unroll") for (int i = 0; i < 8; ++i) {                            \
      float v_ = id_ ? (((8 * g + i) == (16 * ti + c15)) ? SIGMA : 0.f)        \
                     : EXPS((RW).r24[ti * 8 + i]);                             \
      av_[i] = f2bf(v_);                                                       \
    }                                                                          \
    A32_[ti] = av_;                                                            \
    bf16x4 aw_;                                                                \
    _Pragma("unroll") for (int i = 0; i < 4; ++i) {                            \
      float v_ = id_ ? (((32 + 4 * g + i) == (16 * ti + c15)) ? SIGMA : 0.f)   \
                     : EXPS((RW).r12[ti * 4 + i]);                             \
      aw_[i] = f2bf(v_);                                                       \
    }                                                                          \
    A16_[ti] = aw_;                                                            \
  }                                                                            \
  _Pragma("unroll") for (int ti = 0; ti < 3; ++ti)                             \
    _Pragma("unroll") for (int tj = 0; tj < 3; ++tj)                           \
      Cf[ti][tj] = __builtin_amdgcn_mfma_f32_16x16x32_bf16(A32_[ti], Bf32[tj], zz, 0, 0, 0); \
  _Pragma("unroll") for (int ti = 0; ti < 3; ++ti)                             \
    _Pragma("unroll") for (int tj = 0; tj < 3; ++tj)                           \
      Cf[ti][tj] = MFMA16(A16_[ti], Bf16[tj], Cf[ti][tj]);                     \
  if (RECYC) {                                                                 \
    _Pragma("unroll") for (int tj = 0; tj < 3; ++tj) {                         \
      bf16x8 b0_; bf16x4 b1_;                                                  \
      const int sLo_ = ((g & 1) << 5) + c15;                                   \
      _Pragma("unroll") for (int i = 0; i < 8; ++i) {                          \
        const int r_ = i & 3;                                                  \
        const int s_ = sLo_ + ((i & 4) ? 16 : 0);                              \
        float a0_ = __shfl(Cf[0][tj][r_], s_, 64);                             \
        float a1_ = __shfl(Cf[1][tj][r_], s_, 64);                             \
        b0_[i] = f2bf((g >> 1) ? a1_ : a0_);                                   \
      }                                                                        \
      _Pragma("unroll") for (int i = 0; i < 4; ++i) b1_[i] = f2bf(Cf[2][tj][i]); \
      Bf32[tj] = b0_; Bf16[tj] = b1_;                                          \
    }                                                                          \
  }                                                                            \
} while (0)

// ---------------- Phase 1: per-chunk matrix product ----------------
__global__ __launch_bounds__(P1_THREADS, 2) void crf_chunk(
    const float* __restrict__ scores, const int* __restrict__ target,
    const int* __restrict__ mask, unsigned short* __restrict__ Rbuf,
    float* __restrict__ tgbuf)
{
  const int t = threadIdx.x;
  const int lane = t & 63;
  const int wid = t >> 6;
  const int g = lane >> 4;    // 0..3
  const int c15 = lane & 15;  // 0..15

  const int task = blockIdx.x * P1_WAVES + wid;
  const int b = task & (BATCH - 1);
  const int cIdx = task >> 7;
  const int s0 = cIdx * CHUNK;

  // mask (lanes 0..31) / target (lanes 32..63) for this chunk, one reg
  int mt;
  {
    int sl = s0 + (lane & 31);
    mt = (lane < 32) ? mask[(size_t)sl * BATCH + b]
                     : target[(size_t)sl * BATCH + b];
  }

  // tg gather: lane k (k<32) loads scores[s0+k][b][tgt_k] -- all steps CONCURRENT
  float tg = 0.f;
  {
    int tgt_l = __shfl(mt, 32 + (lane & 31), 64);
    if (lane < CHUNK && mt)  // lane<32: mt == mask[s0+lane]
      tg = scores[((size_t)(s0 + lane) * BATCH + b) * TT + tgt_l];
  }

  const float* sb0 = scores + ((size_t)s0 * BATCH + b) * TT;
  const size_t mstride = (size_t)BATCH * TT;

  // prefetch raws for k=0 immediately
  Raw rA, rB;
  CRF_LOAD(rA, sb0);

  // ---- B init = EXACT identity (bf16 1.0 at kk==col)
  bf16x8 Bf32[3];
  bf16x4 Bf16[3];
#pragma unroll
  for (int tj = 0; tj < 3; ++tj) {
    const int col = 16 * tj + c15;
    bf16x8 bv;
#pragma unroll
    for (int i = 0; i < 8; ++i) bv[i] = ((8 * g + i) == col) ? (short)0x3F80 : (short)0;
    Bf32[tj] = bv;
    bf16x4 bw;
#pragma unroll
    for (int i = 0; i < 4; ++i) bw[i] = ((32 + 4 * g + i) == col) ? (short)0x3F80 : (short)0;
    Bf16[tj] = bw;
  }

  f32x4 Cf[3][3];
  const f32x4 zz = {0.f, 0.f, 0.f, 0.f};

  // software-pipelined x2: 32 steps total (k = 0..31)
  int k = 0;
#pragma unroll 1
  for (; k + 2 < CHUNK; k += 2) {
    CRF_LOAD(rB, sb0 + (size_t)(k + 1) * mstride);
    CRF_STEP(rA, k, 1);
    CRF_LOAD(rA, sb0 + (size_t)(k + 2) * mstride);
    CRF_STEP(rB, k + 1, 1);
  }
  // k == 30: steps 30, 31
  CRF_LOAD(rB, sb0 + (size_t)31 * mstride);
  CRF_STEP(rA, 30, 1);
  CRF_STEP(rB, 31, 0);

  // write chunk product R^T (48x48, row-major [j][i]) as bf16
  unsigned short* outp = Rbuf + (size_t)((size_t)cIdx * BATCH + b) * TT;
#pragma unroll
  for (int ti = 0; ti < 3; ++ti)
#pragma unroll
    for (int tj = 0; tj < 3; ++tj)
#pragma unroll
      for (int r = 0; r < 4; ++r) {
        int j = 16 * ti + 4 * g + r;
        int icol = 16 * tj + c15;
        outp[j * T + icol] = (unsigned short)f2bf(Cf[ti][tj][r]);
      }

  // reduce tg across lanes (lanes >= CHUNK hold 0)
#pragma unroll
  for (int d = 1; d < 64; d <<= 1) tg += __shfl_xor(tg, d, 64);
  if (lane == 0) tgbuf[task] = tg;
}

// ---------------- Phase 2: per-batch fold over 16 bf16 chunk matrices ----------------
__global__ __launch_bounds__(64) void crf_fold(
    const float* __restrict__ scores, const unsigned short* __restrict__ Rbuf,
    float* __restrict__ pend)
{
  __shared__ __align__(16) float e[T];
  const int b = blockIdx.x;
  const int j = threadIdx.x & 63;
  const int jr = (j < T) ? j : (T - 1);
  float p = (j < T) ? scores[(size_t)b * TT + START_TAG * T + j] : -1e30f;

  // row j of chunk c: 48 bf16 = 96 B = 6 x uint4 (aligned: 4608*idx + 96*jr)
  uint4 bufA[6], bufB[6];
  {
    const uint4* rA = (const uint4*)(Rbuf + ((size_t)0 * BATCH + b) * TT + (size_t)jr * T);
#pragma unroll
    for (int q = 0; q < 6; ++q) bufA[q] = rA[q];
  }

#define FOLD_STEP(BUF) do {                                                    \
    float sh = __shfl(p, 0, 64);                                               \
    float ev = __expf(p - sh);                                                 \
    if (j < T) e[j] = ev;                                                      \
    asm volatile("s_waitcnt lgkmcnt(0)" ::: "memory");                         \
    __syncthreads();                                                           \
    float acc = 0.f;                                                           \
    _Pragma("unroll") for (int q = 0; q < 6; ++q) {                            \
      const unsigned* u = (const unsigned*)&(BUF)[q];                          \
      _Pragma("unroll") for (int h = 0; h < 4; ++h) {                          \
        float lo = __uint_as_float(u[h] << 16);                                \
        float hi = __uint_as_float(u[h] & 0xffff0000u);                        \
        acc += e[q * 8 + 2 * h] * lo;                                          \
        acc += e[q * 8 + 2 * h + 1] * hi;                                      \
      }                                                                        \
    }                                                                          \
    p = sh + __logf(acc);                                                      \
    __syncthreads();                                                           \
  } while (0)

#pragma unroll 1
  for (int c = 0; c < NCHUNK; c += 2) {
    const uint4* rB = (const uint4*)(Rbuf + ((size_t)(c + 1) * BATCH + b) * TT + (size_t)jr * T);
#pragma unroll
    for (int q = 0; q < 6; ++q) bufB[q] = rB[q];
    FOLD_STEP(bufA);
    if (c + 2 < NCHUNK) {
      const uint4* rA = (const uint4*)(Rbuf + ((size_t)(c + 2) * BATCH + b) * TT + (size_t)jr * T);
#pragma unroll
      for (int q = 0; q < 6; ++q) bufA[q] = rA[q];
    }
    FOLD_STEP(bufB);
  }
#undef FOLD_STEP
  if (j == END_TAG) pend[b] = p;
}

// ---------------- Phase 3: deterministic reduce ----------------
__global__ void crf_final(const float* __restrict__ pend, const float* __restrict__ tgbuf,
                          float* __restrict__ out)
{
  __shared__ float sp[256], st2[256];
  int t = threadIdx.x;
  float ps = (t < BATCH) ? pend[t] : 0.f;
  float ts = 0.f;
  for (int q = t; q < NTASK; q += 256) ts += tgbuf[q];
  sp[t] = ps; st2[t] = ts;
  __syncthreads();
  for (int off = 128; off > 0; off >>= 1) {
    if (t < off) { sp[t] += sp[t + off]; st2[t] += st2[t + off]; }
    __syncthreads();
  }
  if (t == 0) {
    // 16 chunks * 32 steps, each scaled by exactly 2^-7 -> 512*7*ln2
    const float corr = 3584.0f * 0.6931471805599453f;
    out[0] = (sp[0] - st2[0]) / (float)BATCH + corr;
  }
}

// ---------------- Fallback (proven round-1 scan) for small ws ----------------
__global__ __launch_bounds__(512) void fb_scan(
    const float* __restrict__ scores, const int* __restrict__ target,
    const int* __restrict__ mask, float* __restrict__ ws)
{
  __shared__ float tile[2][TT];
  __shared__ float p[T];
  __shared__ float red_m[8][T];
  __shared__ float red_s[8][T];
  __shared__ int lmask[S_LEN];
  __shared__ int ltgt[S_LEN];

  const int b = blockIdx.x;
  const int t = threadIdx.x;
  const int j = t & 63;
  const int ic = t >> 6;
  const bool valid = (j < T);

  lmask[t] = mask[(size_t)t * BATCH + b];
  ltgt[t] = target[(size_t)t * BATCH + b];
  {
    const float4* src = (const float4*)(scores + (size_t)b * TT);
    float4 r0 = src[t]; float4 r1;
    if (t < 64) r1 = src[512 + t];
    float4* dst = (float4*)tile[0];
    dst[t] = r0;
    if (t < 64) dst[512 + t] = r1;
  }
  __syncthreads();
  float tg_local = 0.0f;
  for (int s = 0; s < S_LEN; ++s) {
    const int buf = s & 1;
    float4 r0, r1;
    if (s + 1 < S_LEN) {
      const float4* src = (const float4*)(scores + ((size_t)(s + 1) * BATCH + b) * TT);
      r0 = src[t];
      if (t < 64) r1 = src[512 + t];
    }
    if (s == 0) {
      if (t < T) p[t] = tile[0][START_TAG * T + t];
      if (t == 0 && lmask[0]) tg_local += tile[0][ltgt[0]];
    } else {
      if (valid) {
        const int i0 = ic * 6;
        float x[6]; float m = -1e30f;
#pragma unroll
        for (int kq = 0; kq < 6; ++kq) {
          x[kq] = tile[buf][(i0 + kq) * T + j] + p[i0 + kq];
          m = fmaxf(m, x[kq]);
        }
        float sum = 0.0f;
#pragma unroll
        for (int kq = 0; kq < 6; ++kq) sum += __expf(x[kq] - m);
        red_m[ic][j] = m; red_s[ic][j] = sum;
      }
      if (t == 0 && lmask[s]) tg_local += tile[buf][ltgt[s]];
    }
    __syncthreads();
    if (s > 0 && t < T) {
      float M = red_m[0][t];
#pragma unroll
      for (int g2 = 1; g2 < 8; ++g2) M = fmaxf(M, red_m[g2][t]);
      float Ssum = 0.0f;
#pragma unroll
      for (int g2 = 0; g2 < 8; ++g2) Ssum += red_s[g2][t] * __expf(red_m[g2][t] - M);
      float cur = M + __logf(Ssum);
      if (lmask[s]) p[t] = cur;
    }
    if (s + 1 < S_LEN) {
      float4* dst = (float4*)tile[buf ^ 1];
      dst[t] = r0;
      if (t < 64) dst[512 + t] = r1;
    }
    __syncthreads();
  }
  if (t == 0) ws[b] = p[END_TAG] - tg_local;
}

__global__ void fb_reduce(const float* __restrict__ ws, float* __restrict__ out)
{
  __shared__ float sh[BATCH];
  const int t = threadIdx.x;
  if (t < BATCH) sh[t] = ws[t];
  __syncthreads();
  if (t == 0) {
    float s = 0.0f;
    for (int k = 0; k < BATCH; ++k) s += sh[k];
    out[0] = s / (float)BATCH;
  }
}

extern "C" void kernel_launch(void* const* d_in, const int* in_sizes, int n_in,
                              void* d_out, int out_size, void* d_ws, size_t ws_size,
                              hipStream_t stream)
{
  const float* scores = (const float*)d_in[0];
  const int* target = (const int*)d_in[1];
  const int* mask = (const int*)d_in[2];
  float* out = (float*)d_out;

  const size_t RB_BYTES = (size_t)NTASK * TT * 2;  // bf16 chunk products
  const size_t need = RB_BYTES + (size_t)NTASK * 4 + (size_t)BATCH * 4;

  if (ws_size >= need) {
    unsigned short* Rbuf = (unsigned short*)d_ws;
    float* tgbuf = (float*)((char*)d_ws + RB_BYTES);
    float* pend = tgbuf + NTASK;
    crf_chunk<<<P1_BLOCKS, P1_THREADS, 0, stream>>>(scores, target, mask, Rbuf, tgbuf);
    crf_fold<<<BATCH, 64, 0, stream>>>(scores, Rbuf, pend);
    crf_final<<<1, 256, 0, stream>>>(pend, tgbuf, out);
  } else {
    float* ws = (float*)d_ws;
    fb_scan<<<BATCH, 512, 0, stream>>>(scores, target, mask, ws);
    fb_reduce<<<1, 128, 0, stream>>>(ws, out);
  }
}